// Round 15
// baseline (142.035 us; speedup 1.0000x reference)
//
#include <hip/hip_runtime.h>
#include <hip/hip_bf16.h>
#include <math.h>

#define M_NODES 50000
#define IN_F    128
#define OUT_F   128
#define NH      3
#define ED_F    16
#define NE      800000
#define HO      (NH * OUT_F)   // 384
#define NEG_SLOPE 0.2f
#define LN_EPS    1e-5f
#define CAP     64             // node bucket capacity; P(deg>64)~1e-18

// k_pre block ranges (256-thread blocks)
#define PB_ATTN 782                   // 64 nodes/block (4 lanes per node)
#define PB_FILL (PB_ATTN + 1563)      // 2345: 512 edges/block (2 per thread)
#define PB_PQ   (PB_FILL + 192)       // 2537: 2 outputs/block
#define PB_TOT  (PB_PQ + 128)         // 2665: bias2, 1 column/block

typedef __attribute__((ext_vector_type(8))) short bf16x8;
typedef __attribute__((ext_vector_type(4))) float f32x4;

__device__ __forceinline__ float b2f(unsigned short u) {
    unsigned int x = ((unsigned int)u) << 16;
    return __uint_as_float(x);
}
__device__ __forceinline__ unsigned short f2b(float f) {
    __hip_bfloat16 h = __float2bfloat16(f);
    return *(unsigned short*)&h;
}

// ---------------------------------------------------------------------------
// K_small: folded attention vectors, one block (64 thr) per output.
// small layout: [0,384) srcT h*128+k | [384,768) dstT h*128+k | [768,816) We(d*3+h)
// ---------------------------------------------------------------------------
__global__ __launch_bounds__(64)
void k_small(const float* __restrict__ W, const float* __restrict__ Wed,
             const float* __restrict__ a_s, const float* __restrict__ a_d,
             const float* __restrict__ a_e, float* __restrict__ small)
{
    int o = blockIdx.x, l = threadIdx.x;
    if (o < 384) {
        int k = o / 3, h = o - k * 3;
        float wA = W[(size_t)k * HO + h * 128 + l];
        float wB = W[(size_t)k * HO + h * 128 + 64 + l];
        float s1 = wA * a_s[h * 128 + l] + wB * a_s[h * 128 + 64 + l];
        float s2 = wA * a_d[h * 128 + l] + wB * a_d[h * 128 + 64 + l];
        #pragma unroll
        for (int s = 32; s; s >>= 1) { s1 += __shfl_xor(s1, s); s2 += __shfl_xor(s2, s); }
        if (l == 0) { small[h * 128 + k] = s1; small[384 + h * 128 + k] = s2; }
    } else {
        int u = o - 384;
        int d = u / 3, h = u - d * 3;
        float s = Wed[(size_t)d * HO + h * 128 + l] * a_e[h * 128 + l]
                + Wed[(size_t)d * HO + h * 128 + 64 + l] * a_e[h * 128 + 64 + l];
        #pragma unroll
        for (int ss = 32; ss; ss >>= 1) s += __shfl_xor(s, ss);
        if (l == 0) small[768 + u] = s;
    }
}

// ---------------------------------------------------------------------------
// K_pre mega-kernel (256-thr blocks): 4 block-ranged sections that overlap
// on the machine. Sections MUST stay merged (r11 vs r13: ~15us of overlap).
//  [0, 782)       attn: 64 nodes/block, 4 lanes/node; asrc/adst + x->bf16.
//  [782, 2345)    fill: 512 edges/block, 2/thread. Writes: aebuf4[e] record
//                 COALESCED (by edge id) + eidb 4B scatter (3x less writeback
//                 than the old 16B record scatter).
//  [2345, 2537)   prep_q: 2 outputs/block
//  [2537, 2665)   bias2: 1 column/block, 256-thread reduce
// ---------------------------------------------------------------------------
__global__ __launch_bounds__(256)
void k_pre(const float* __restrict__ x, const float* __restrict__ W,
           const float* __restrict__ lw, const float* __restrict__ gb,
           const float* __restrict__ lb, const int* __restrict__ ei,
           const float* __restrict__ ea, const float* __restrict__ small,
           float4* __restrict__ asrc4, float4* __restrict__ adst4,
           unsigned short* __restrict__ x16, int* __restrict__ cursor,
           int* __restrict__ eidb, float4* __restrict__ aebuf4,
           unsigned short* __restrict__ Qt, float* __restrict__ b2)
{
    int b = blockIdx.x, t = threadIdx.x;
    if (b < PB_ATTN) {
        // padded LDS: row = s*12 + h*4 + j (24 rows x 36 floats), conflict-free
        __shared__ float smp[24 * 36];
        for (int i = t; i < 768; i += 256) {
            int s = i / 384;
            int rem = i - s * 384;
            int h = rem >> 7, rem2 = rem & 127;
            int j = rem2 >> 5, col = rem2 & 31;
            smp[(s * 12 + h * 4 + j) * 36 + col] = small[i];
        }
        __syncthreads();
        int g = t >> 2, j = t & 3;
        int n = b * 64 + g;
        if (n >= M_NODES) return;
        const float4* xr = (const float4*)x + (size_t)n * 32 + j * 8;
        float4 xv[8];
        #pragma unroll
        for (int i = 0; i < 8; ++i) xv[i] = xr[i];
        unsigned int pk[16];
        #pragma unroll
        for (int i = 0; i < 8; ++i) {
            pk[2*i]   = (unsigned int)f2b(xv[i].x) | ((unsigned int)f2b(xv[i].y) << 16);
            pk[2*i+1] = (unsigned int)f2b(xv[i].z) | ((unsigned int)f2b(xv[i].w) << 16);
        }
        uint4* xo = (uint4*)(x16 + (size_t)n * IN_F + j * 32);
        xo[0] = make_uint4(pk[0],  pk[1],  pk[2],  pk[3]);
        xo[1] = make_uint4(pk[4],  pk[5],  pk[6],  pk[7]);
        xo[2] = make_uint4(pk[8],  pk[9],  pk[10], pk[11]);
        xo[3] = make_uint4(pk[12], pk[13], pk[14], pk[15]);
        float p[3] = {0.f,0.f,0.f}, q[3] = {0.f,0.f,0.f};
        #pragma unroll
        for (int i = 0; i < 8; ++i) {
            float4 v = xv[i];
            #pragma unroll
            for (int h = 0; h < 3; ++h) {
                float4 ws = *(const float4*)&smp[(h * 4 + j) * 36 + i * 4];
                float4 wd = *(const float4*)&smp[(12 + h * 4 + j) * 36 + i * 4];
                p[h] += v.x * ws.x + v.y * ws.y + v.z * ws.z + v.w * ws.w;
                q[h] += v.x * wd.x + v.y * wd.y + v.z * wd.z + v.w * wd.w;
            }
        }
        #pragma unroll
        for (int h = 0; h < 3; ++h) {
            p[h] += __shfl_xor(p[h], 1); p[h] += __shfl_xor(p[h], 2);
            q[h] += __shfl_xor(q[h], 1); q[h] += __shfl_xor(q[h], 2);
        }
        if (j == 0) {
            asrc4[n] = make_float4(p[0], p[1], p[2], 0.f);
            adst4[n] = make_float4(q[0], q[1], q[2], 0.f);
        }
    } else if (b < PB_FILL) {
        int e0 = (b - PB_ATTN) * 512 + t;      // edges e0 and e0+256
        int e1 = e0 + 256;
        bool v0 = e0 < NE;
        bool v1 = e1 < NE;
        int r0 = 0, c0 = 0, r1 = 0, c1 = 0, pos0 = 0, pos1 = 0;
        if (v0) {
            r0 = ei[e0]; c0 = ei[NE + e0];
            pos0 = atomicAdd(&cursor[c0], 1);
        }
        if (v1) {
            r1 = ei[e1]; c1 = ei[NE + e1];
            pos1 = atomicAdd(&cursor[c1], 1);
        }
        const float* Wev = small + 768;
        if (v0) {
            const float4* p = (const float4*)(ea + (size_t)e0 * 16);
            float4 q0 = p[0], q1 = p[1], q2 = p[2], q3 = p[3];
            float v[16] = {q0.x,q0.y,q0.z,q0.w, q1.x,q1.y,q1.z,q1.w,
                           q2.x,q2.y,q2.z,q2.w, q3.x,q3.y,q3.z,q3.w};
            float ae[3];
            #pragma unroll
            for (int h = 0; h < 3; ++h) {
                float s = 0.f;
                #pragma unroll
                for (int d = 0; d < 16; ++d) s += v[d] * Wev[d * 3 + h];
                ae[h] = s;
            }
            aebuf4[e0] = make_float4(__int_as_float(r0), ae[0], ae[1], ae[2]); // coalesced
            if (pos0 < CAP) eidb[(size_t)c0 * CAP + pos0] = e0;               // 4B scatter
        }
        if (v1) {
            const float4* p = (const float4*)(ea + (size_t)e1 * 16);
            float4 q0 = p[0], q1 = p[1], q2 = p[2], q3 = p[3];
            float v[16] = {q0.x,q0.y,q0.z,q0.w, q1.x,q1.y,q1.z,q1.w,
                           q2.x,q2.y,q2.z,q2.w, q3.x,q3.y,q3.z,q3.w};
            float ae[3];
            #pragma unroll
            for (int h = 0; h < 3; ++h) {
                float s = 0.f;
                #pragma unroll
                for (int d = 0; d < 16; ++d) s += v[d] * Wev[d * 3 + h];
                ae[h] = s;
            }
            aebuf4[e1] = make_float4(__int_as_float(r1), ae[0], ae[1], ae[2]); // coalesced
            if (pos1 < CAP) eidb[(size_t)c1 * CAP + pos1] = e1;               // 4B scatter
        }
    } else if (b < PB_PQ) {
        int i = (b - PB_FILL) * 2 + (t >> 7);  // 0..383 = h*128+tt
        int h = i >> 7, tt = i & 127;
        int j = t & 127;
        float s = 0.f;
        const float* wrow = W + (size_t)tt * HO + h * 128;
        const float* lcol = lw + (size_t)(h * 128) * 128 + j;
        #pragma unroll 4
        for (int c = 0; c < 128; ++c)
            s += wrow[c] * lcol[(size_t)c * 128];
        Qt[(size_t)j * HO + i] = f2b(s);
    } else {
        __shared__ float red[4];
        int j = b - PB_PQ;
        float s = 0.f;
        for (int i = t; i < HO; i += 256) s += gb[i] * lw[(size_t)i * 128 + j];
        #pragma unroll
        for (int k = 32; k; k >>= 1) s += __shfl_xor(s, k);
        int w = t >> 6, lane = t & 63;
        if (lane == 0) red[w] = s;
        __syncthreads();
        if (t == 0) b2[j] = lb[j] + red[0] + red[1] + red[2] + red[3];
    }
}

// ---------------------------------------------------------------------------
// K_agg v8: TWO NODES PER WAVE (half-wave per node), 8 nodes / 256-thr block.
// Phase A now: eidb coalesced read -> aebuf4[e] gather (L3-resident 12.8MB).
// ---------------------------------------------------------------------------
__global__ __launch_bounds__(256)
void k_agg(const int* __restrict__ cursor, const int* __restrict__ eidb,
           const float4* __restrict__ aebuf4,
           const float4* __restrict__ asrc4, const float4* __restrict__ adst4,
           const unsigned short* __restrict__ x16, unsigned short* __restrict__ sbar)
{
    __shared__ float4 wsh[4][2][CAP];
    int t = threadIdx.x;
    int wv = t >> 6, l = t & 63;
    int h = l >> 5, q = l & 31;
    int n = blockIdx.x * 8 + wv * 2 + h;
    int ne_raw = cursor[n];
    int ne = ne_raw < CAP ? ne_raw : CAP;
    float4 ad = adst4[n];
    const char* xb = (const char*)x16;

    float a0[4] = {0.f,0.f,0.f,0.f};
    float a1[4] = {0.f,0.f,0.f,0.f};
    float a2[4] = {0.f,0.f,0.f,0.f};
    float pd0=0.f, pd1=0.f, pd2=0.f, pa0=0.f, pa1=0.f, pa2=0.f;

    // ---- phase A: half-wave covers slots q and q+32 of its node ----
    #pragma unroll
    for (int base = 0; base < CAP; base += 32) {
        int i = base + q;
        if (i < ne) {
            int e = eidb[(size_t)n * CAP + i];
            float4 m0 = aebuf4[e];
            int r = __float_as_int(m0.x);
            float4 as = asrc4[r];
            float al0 = m0.y + as.x + ad.x;
            float al1 = m0.z + as.y + ad.y;
            float al2 = m0.w + as.z + ad.z;
            al0 = (al0 >= 0.f) ? al0 : NEG_SLOPE * al0;
            al1 = (al1 >= 0.f) ? al1 : NEG_SLOPE * al1;
            al2 = (al2 >= 0.f) ? al2 : NEG_SLOPE * al2;
            float w0 = __expf(al0), w1 = __expf(al1), w2 = __expf(al2);
            pa0 += m0.y; pa1 += m0.z; pa2 += m0.w;
            pd0 += w0; pd1 += w1; pd2 += w2;
            wsh[wv][h][i] = make_float4(w0, w1, w2, m0.x);
        }
    }
    // wave-synchronous LDS: drain writes before any lane reads
    asm volatile("s_waitcnt lgkmcnt(0)" ::: "memory");
    __builtin_amdgcn_sched_barrier(0);

    // ---- 5-step butterfly within each half-wave (halves stay separate) ----
    #pragma unroll
    for (int s = 16; s; s >>= 1) {
        pd0 += __shfl_xor(pd0, s); pd1 += __shfl_xor(pd1, s); pd2 += __shfl_xor(pd2, s);
        pa0 += __shfl_xor(pa0, s); pa1 += __shfl_xor(pa1, s); pa2 += __shfl_xor(pa2, s);
    }

    // ---- phase B: half-wave walks its node's edges; lane q -> cols 4q..4q+3
    #pragma unroll 2
    for (int i = 0; i < ne; ++i) {
        float4 m = wsh[wv][h][i];
        int r = __float_as_int(m.w);
        uint2 v = *(const uint2*)(xb + (size_t)r * 256 + q * 8);
        float e0 = __uint_as_float(v.x << 16);
        float e1 = __uint_as_float(v.x & 0xFFFF0000u);
        float e2 = __uint_as_float(v.y << 16);
        float e3 = __uint_as_float(v.y & 0xFFFF0000u);
        a0[0] += m.x * e0; a0[1] += m.x * e1; a0[2] += m.x * e2; a0[3] += m.x * e3;
        a1[0] += m.y * e0; a1[1] += m.y * e1; a1[2] += m.y * e2; a1[3] += m.y * e3;
        a2[0] += m.z * e0; a2[1] += m.z * e1; a2[2] += m.z * e2; a2[3] += m.z * e3;
    }

    // ---- self-loop: attr = mean of incoming -> ae_loop = mean of ae ----
    float4 as = asrc4[n];
    float inv = 1.0f / fmaxf((float)ne_raw, 1.0f);
    float al0 = as.x + ad.x + pa0 * inv;
    float al1 = as.y + ad.y + pa1 * inv;
    float al2 = as.z + ad.z + pa2 * inv;
    al0 = (al0 >= 0.f) ? al0 : NEG_SLOPE * al0;
    al1 = (al1 >= 0.f) ? al1 : NEG_SLOPE * al1;
    al2 = (al2 >= 0.f) ? al2 : NEG_SLOPE * al2;
    float w0 = __expf(al0), w1 = __expf(al1), w2 = __expf(al2);
    float d0 = pd0 + w0, d1 = pd1 + w1, d2 = pd2 + w2;
    float i0 = 1.f / d0, i1 = 1.f / d1, i2 = 1.f / d2;

    // ---- epilogue: all 64 lanes store (each half its node) ----
    uint2 xv = *(const uint2*)(xb + (size_t)n * 256 + q * 8);
    float e0 = __uint_as_float(xv.x << 16);
    float e1 = __uint_as_float(xv.x & 0xFFFF0000u);
    float e2 = __uint_as_float(xv.y << 16);
    float e3 = __uint_as_float(xv.y & 0xFFFF0000u);
    uint2* ob = (uint2*)(sbar + (size_t)n * HO);
    unsigned int p0, p1;
    p0 = (unsigned int)f2b((a0[0] + w0 * e0) * i0) | ((unsigned int)f2b((a0[1] + w0 * e1) * i0) << 16);
    p1 = (unsigned int)f2b((a0[2] + w0 * e2) * i0) | ((unsigned int)f2b((a0[3] + w0 * e3) * i0) << 16);
    ob[q] = make_uint2(p0, p1);
    p0 = (unsigned int)f2b((a1[0] + w1 * e0) * i1) | ((unsigned int)f2b((a1[1] + w1 * e1) * i1) << 16);
    p1 = (unsigned int)f2b((a1[2] + w1 * e2) * i1) | ((unsigned int)f2b((a1[3] + w1 * e3) * i1) << 16);
    ob[32 + q] = make_uint2(p0, p1);
    p0 = (unsigned int)f2b((a2[0] + w2 * e0) * i2) | ((unsigned int)f2b((a2[1] + w2 * e1) * i2) << 16);
    p1 = (unsigned int)f2b((a2[2] + w2 * e2) * i2) | ((unsigned int)f2b((a2[3] + w2 * e3) * i2) << 16);
    ob[64 + q] = make_uint2(p0, p1);
}

// ---------------------------------------------------------------------------
// MFMA GEMM + bias + residual + LayerNorm fused:
// out[M][128] = LN( sbar[M][384] @ Q + b2 + x )   Bt = Qt [128][384]
// ---------------------------------------------------------------------------
__global__ __launch_bounds__(256)
void k_mm2_ln(const unsigned short* __restrict__ A, const unsigned short* __restrict__ Bt,
              const float* __restrict__ bias, const float* __restrict__ xres,
              const float* __restrict__ lng, const float* __restrict__ lnb,
              float* __restrict__ out)
{
    __shared__ char lds[24576]; // As [0,8192), Bs [8192,24576)
    const int bm = blockIdx.x * 64;
    const int tid = threadIdx.x, w = tid >> 6, lane = tid & 63;
    const int lrow = lane & 15, lk = lane >> 4;
    const short z0 = 0;
    f32x4 acc[8];
    #pragma unroll
    for (int f = 0; f < 8; ++f) { acc[f][0]=0.f; acc[f][1]=0.f; acc[f][2]=0.f; acc[f][3]=0.f; }

    for (int k0 = 0; k0 < 384; k0 += 64) {
        #pragma unroll
        for (int it = 0; it < 2; ++it) {
            int c = tid + it * 256;
            int row = c >> 3, o = c & 7;
            int grow = bm + row;
            bf16x8 v = {z0,z0,z0,z0,z0,z0,z0,z0};
            if (grow < M_NODES) v = *(const bf16x8*)(A + (size_t)grow * 384 + k0 + o * 8);
            int b = (row * 128 + o * 16) ^ ((row & 7) << 4);
            *(bf16x8*)(lds + b) = v;
        }
        #pragma unroll
        for (int it = 0; it < 4; ++it) {
            int c = tid + it * 256;
            int row = c >> 3, o = c & 7;   // row 0..127
            bf16x8 v = *(const bf16x8*)(Bt + (size_t)row * 384 + k0 + o * 8);
            int b = 8192 + ((row * 128 + o * 16) ^ ((row & 7) << 4));
            *(bf16x8*)(lds + b) = v;
        }
        __syncthreads();
        #pragma unroll
        for (int kk = 0; kk < 2; ++kk) {
            int ar = w * 16 + lrow;
            bf16x8 a = *(const bf16x8*)(lds + ((ar * 128 + kk * 64 + lk * 16) ^ ((lrow & 7) << 4)));
            #pragma unroll
            for (int f = 0; f < 8; ++f) {
                int br = 16 * f + lrow;
                bf16x8 bb = *(const bf16x8*)(lds + 8192 + ((br * 128 + kk * 64 + lk * 16) ^ ((lrow & 7) << 4)));
                acc[f] = __builtin_amdgcn_mfma_f32_16x16x32_bf16(a, bb, acc[f], 0, 0, 0);
            }
        }
        __syncthreads();
    }

    // fused bias + residual + LayerNorm epilogue
    int cols[8]; float bs[8], gg[8], bbv[8];
    #pragma unroll
    for (int f = 0; f < 8; ++f) {
        cols[f] = 16 * f + lrow;
        bs[f] = bias[cols[f]];
        gg[f] = lng[cols[f]];
        bbv[f] = lnb[cols[f]];
    }
    #pragma unroll
    for (int rg = 0; rg < 4; ++rg) {
        int grow = bm + w * 16 + lk * 4 + rg;
        bool ok = grow < M_NODES;
        float h[8];
        float s = 0.f;
        #pragma unroll
        for (int f = 0; f < 8; ++f) {
            float hv = 0.f;
            if (ok) hv = acc[f][rg] + bs[f] + xres[(size_t)grow * 128 + cols[f]];
            h[f] = hv;
            s += hv;
        }
        #pragma unroll
        for (int m = 1; m < 16; m <<= 1) s += __shfl_xor(s, m);
        float mu = s * (1.0f / 128.0f);
        float vv = 0.f;
        #pragma unroll
        for (int f = 0; f < 8; ++f) { float d = h[f] - mu; vv += d * d; }
        #pragma unroll
        for (int m = 1; m < 16; m <<= 1) vv += __shfl_xor(vv, m);
        float rs = rsqrtf(vv * (1.0f / 128.0f) + LN_EPS);
        if (ok) {
            #pragma unroll
            for (int f = 0; f < 8; ++f)
                out[(size_t)grow * 128 + cols[f]] = (h[f] - mu) * rs * gg[f] + bbv[f];
        }
    }
}

// ---------------------------------------------------------------------------
extern "C" void kernel_launch(void* const* d_in, const int* in_sizes, int n_in,
                              void* d_out, int out_size, void* d_ws, size_t ws_size,
                              hipStream_t stream)
{
    const float* x    = (const float*)d_in[0];
    const int*   ei   = (const int*)  d_in[1];
    const float* ea   = (const float*)d_in[2];
    const float* W    = (const float*)d_in[3];
    const float* Wed  = (const float*)d_in[4];
    const float* asv  = (const float*)d_in[5];
    const float* adv  = (const float*)d_in[6];
    const float* aev  = (const float*)d_in[7];
    const float* gb   = (const float*)d_in[8];
    const float* lw   = (const float*)d_in[9];
    const float* lb   = (const float*)d_in[10];
    const float* lng  = (const float*)d_in[11];
    const float* lnb  = (const float*)d_in[12];
    float* out = (float*)d_out;

    char* wsp = (char*)d_ws;
    size_t off = 0;
    auto alloc = [&](size_t bytes) -> void* {
        void* p = wsp + off;
        off += bytes;
        off = (off + 255) & ~(size_t)255;
        return p;
    };

    // zero-init region (cursor only)
    int*   cursor  = (int*)  alloc((size_t)M_NODES * 4);
    size_t zero_bytes = off;
    float* small   = (float*)alloc(816 * 4);
    float* b2      = (float*)alloc(128 * 4);
    float4* asrc4  = (float4*)alloc((size_t)M_NODES * 16);
    float4* adst4  = (float4*)alloc((size_t)M_NODES * 16);
    int*   eidb    = (int*)  alloc((size_t)M_NODES * CAP * 4);     // 12.8 MB
    float4* aebuf4 = (float4*)alloc((size_t)NE * 16);              // 12.8 MB (L3-resident)
    unsigned short* x16   = (unsigned short*)alloc((size_t)M_NODES * IN_F * 2);
    unsigned short* Qt16  = (unsigned short*)alloc((size_t)OUT_F * HO * 2);
    unsigned short* sbar  = (unsigned short*)alloc((size_t)M_NODES * HO * 2);
    (void)ws_size; (void)in_sizes; (void)n_in; (void)out_size;

    (void)hipMemsetAsync(d_ws, 0, zero_bytes, stream);

    k_small<<<432, 64, 0, stream>>>(W, Wed, asv, adv, aev, small);
    k_pre<<<PB_TOT, 256, 0, stream>>>(x, W, lw, gb, lb, ei, ea, small,
                                      asrc4, adst4, x16, cursor, eidb, aebuf4, Qt16, b2);
    k_agg<<<M_NODES / 8, 256, 0, stream>>>(cursor, eidb, aebuf4, asrc4, adst4, x16, sbar);
    k_mm2_ln<<<(M_NODES + 63) / 64, 256, 0, stream>>>(sbar, Qt16, b2, x, lng, lnb, out);
}

// Round 16
// 132.595 us; speedup vs baseline: 1.0712x; 1.0712x over previous
//
#include <hip/hip_runtime.h>
#include <hip/hip_bf16.h>
#include <math.h>

#define M_NODES 50000
#define IN_F    128
#define OUT_F   128
#define NH      3
#define ED_F    16
#define NE      800000
#define HO      (NH * OUT_F)   // 384
#define NEG_SLOPE 0.2f
#define LN_EPS    1e-5f
#define CAP     64             // node bucket capacity; P(deg>64)~1e-18

// k_pre block ranges (256-thread blocks)
#define PB_ATTN 782                   // 64 nodes/block (4 lanes per node)
#define PB_FILL (PB_ATTN + 782)       // 1564: 1024 edges/block (4 per thread)
#define PB_PQ   (PB_FILL + 192)       // 1756: 2 outputs/block
#define PB_TOT  (PB_PQ + 128)         // 1884: bias2, 1 column/block

typedef __attribute__((ext_vector_type(8))) short bf16x8;
typedef __attribute__((ext_vector_type(4))) float f32x4;

__device__ __forceinline__ float b2f(unsigned short u) {
    unsigned int x = ((unsigned int)u) << 16;
    return __uint_as_float(x);
}
__device__ __forceinline__ unsigned short f2b(float f) {
    __hip_bfloat16 h = __float2bfloat16(f);
    return *(unsigned short*)&h;
}

// ---------------------------------------------------------------------------
// K_small: folded attention vectors, one block (64 thr) per output.
// small layout: [0,384) srcT h*128+k | [384,768) dstT h*128+k | [768,816) We(d*3+h)
// ---------------------------------------------------------------------------
__global__ __launch_bounds__(64)
void k_small(const float* __restrict__ W, const float* __restrict__ Wed,
             const float* __restrict__ a_s, const float* __restrict__ a_d,
             const float* __restrict__ a_e, float* __restrict__ small)
{
    int o = blockIdx.x, l = threadIdx.x;
    if (o < 384) {
        int k = o / 3, h = o - k * 3;
        float wA = W[(size_t)k * HO + h * 128 + l];
        float wB = W[(size_t)k * HO + h * 128 + 64 + l];
        float s1 = wA * a_s[h * 128 + l] + wB * a_s[h * 128 + 64 + l];
        float s2 = wA * a_d[h * 128 + l] + wB * a_d[h * 128 + 64 + l];
        #pragma unroll
        for (int s = 32; s; s >>= 1) { s1 += __shfl_xor(s1, s); s2 += __shfl_xor(s2, s); }
        if (l == 0) { small[h * 128 + k] = s1; small[384 + h * 128 + k] = s2; }
    } else {
        int u = o - 384;
        int d = u / 3, h = u - d * 3;
        float s = Wed[(size_t)d * HO + h * 128 + l] * a_e[h * 128 + l]
                + Wed[(size_t)d * HO + h * 128 + 64 + l] * a_e[h * 128 + 64 + l];
        #pragma unroll
        for (int ss = 32; ss; ss >>= 1) s += __shfl_xor(s, ss);
        if (l == 0) small[768 + u] = s;
    }
}

// ---------------------------------------------------------------------------
// K_pre mega-kernel (256-thr blocks): 4 block-ranged sections that overlap
// on the machine. Sections MUST stay merged (r11 vs r13: ~15us of overlap).
// Scatter-writeback lesson (r15): any <=64B scatter costs one 64B sector;
// keep ONE 16B scattered record per edge, nothing more.
//  [0, 782)       attn: 64 nodes/block, 4 lanes/node; asrc/adst + x->bf16.
//  [782, 1564)    fill: 1024 edges/block, FOUR independent chains per thread
//                 (atomics issued back-to-back, then 4 ae+store chains).
//  [1564, 1756)   prep_q: 2 outputs/block
//  [1756, 1884)   bias2: 1 column/block, 256-thread reduce
// ---------------------------------------------------------------------------
__global__ __launch_bounds__(256)
void k_pre(const float* __restrict__ x, const float* __restrict__ W,
           const float* __restrict__ lw, const float* __restrict__ gb,
           const float* __restrict__ lb, const int* __restrict__ ei,
           const float* __restrict__ ea, const float* __restrict__ small,
           float4* __restrict__ asrc4, float4* __restrict__ adst4,
           unsigned short* __restrict__ x16, int* __restrict__ cursor,
           float4* __restrict__ edata,
           unsigned short* __restrict__ Qt, float* __restrict__ b2)
{
    int b = blockIdx.x, t = threadIdx.x;
    if (b < PB_ATTN) {
        // padded LDS: row = s*12 + h*4 + j (24 rows x 36 floats), conflict-free
        __shared__ float smp[24 * 36];
        for (int i = t; i < 768; i += 256) {
            int s = i / 384;
            int rem = i - s * 384;
            int h = rem >> 7, rem2 = rem & 127;
            int j = rem2 >> 5, col = rem2 & 31;
            smp[(s * 12 + h * 4 + j) * 36 + col] = small[i];
        }
        __syncthreads();
        int g = t >> 2, j = t & 3;
        int n = b * 64 + g;
        if (n >= M_NODES) return;
        const float4* xr = (const float4*)x + (size_t)n * 32 + j * 8;
        float4 xv[8];
        #pragma unroll
        for (int i = 0; i < 8; ++i) xv[i] = xr[i];
        unsigned int pk[16];
        #pragma unroll
        for (int i = 0; i < 8; ++i) {
            pk[2*i]   = (unsigned int)f2b(xv[i].x) | ((unsigned int)f2b(xv[i].y) << 16);
            pk[2*i+1] = (unsigned int)f2b(xv[i].z) | ((unsigned int)f2b(xv[i].w) << 16);
        }
        uint4* xo = (uint4*)(x16 + (size_t)n * IN_F + j * 32);
        xo[0] = make_uint4(pk[0],  pk[1],  pk[2],  pk[3]);
        xo[1] = make_uint4(pk[4],  pk[5],  pk[6],  pk[7]);
        xo[2] = make_uint4(pk[8],  pk[9],  pk[10], pk[11]);
        xo[3] = make_uint4(pk[12], pk[13], pk[14], pk[15]);
        float p[3] = {0.f,0.f,0.f}, q[3] = {0.f,0.f,0.f};
        #pragma unroll
        for (int i = 0; i < 8; ++i) {
            float4 v = xv[i];
            #pragma unroll
            for (int h = 0; h < 3; ++h) {
                float4 ws = *(const float4*)&smp[(h * 4 + j) * 36 + i * 4];
                float4 wd = *(const float4*)&smp[(12 + h * 4 + j) * 36 + i * 4];
                p[h] += v.x * ws.x + v.y * ws.y + v.z * ws.z + v.w * ws.w;
                q[h] += v.x * wd.x + v.y * wd.y + v.z * wd.z + v.w * wd.w;
            }
        }
        #pragma unroll
        for (int h = 0; h < 3; ++h) {
            p[h] += __shfl_xor(p[h], 1); p[h] += __shfl_xor(p[h], 2);
            q[h] += __shfl_xor(q[h], 1); q[h] += __shfl_xor(q[h], 2);
        }
        if (j == 0) {
            asrc4[n] = make_float4(p[0], p[1], p[2], 0.f);
            adst4[n] = make_float4(q[0], q[1], q[2], 0.f);
        }
    } else if (b < PB_FILL) {
        int eb = (b - PB_ATTN) * 1024 + t;     // edges eb + {0,256,512,768}
        int e[4];
        bool v[4];
        int r[4], c[4], pos[4];
        #pragma unroll
        for (int k = 0; k < 4; ++k) {
            e[k] = eb + k * 256;
            v[k] = e[k] < NE;
        }
        #pragma unroll
        for (int k = 0; k < 4; ++k) {
            if (v[k]) {
                r[k] = ei[e[k]];
                c[k] = ei[NE + e[k]];
                pos[k] = atomicAdd(&cursor[c[k]], 1);
            }
        }
        const float* Wev = small + 768;
        #pragma unroll
        for (int k = 0; k < 4; ++k) {
            if (v[k]) {
                const float4* p = (const float4*)(ea + (size_t)e[k] * 16);
                float4 q0 = p[0], q1 = p[1], q2 = p[2], q3 = p[3];
                float vv[16] = {q0.x,q0.y,q0.z,q0.w, q1.x,q1.y,q1.z,q1.w,
                                q2.x,q2.y,q2.z,q2.w, q3.x,q3.y,q3.z,q3.w};
                float ae0 = 0.f, ae1 = 0.f, ae2 = 0.f;
                #pragma unroll
                for (int d = 0; d < 16; ++d) {
                    ae0 += vv[d] * Wev[d * 3 + 0];
                    ae1 += vv[d] * Wev[d * 3 + 1];
                    ae2 += vv[d] * Wev[d * 3 + 2];
                }
                if (pos[k] < CAP)
                    edata[(size_t)c[k] * CAP + pos[k]] =
                        make_float4(__int_as_float(r[k]), ae0, ae1, ae2);
            }
        }
    } else if (b < PB_PQ) {
        int i = (b - PB_FILL) * 2 + (t >> 7);  // 0..383 = h*128+tt
        int h = i >> 7, tt = i & 127;
        int j = t & 127;
        float s = 0.f;
        const float* wrow = W + (size_t)tt * HO + h * 128;
        const float* lcol = lw + (size_t)(h * 128) * 128 + j;
        #pragma unroll 4
        for (int c = 0; c < 128; ++c)
            s += wrow[c] * lcol[(size_t)c * 128];
        Qt[(size_t)j * HO + i] = f2b(s);
    } else {
        __shared__ float red[4];
        int j = b - PB_PQ;
        float s = 0.f;
        for (int i = t; i < HO; i += 256) s += gb[i] * lw[(size_t)i * 128 + j];
        #pragma unroll
        for (int k = 32; k; k >>= 1) s += __shfl_xor(s, k);
        int w = t >> 6, lane = t & 63;
        if (lane == 0) red[w] = s;
        __syncthreads();
        if (t == 0) b2[j] = lb[j] + red[0] + red[1] + red[2] + red[3];
    }
}

// ---------------------------------------------------------------------------
// K_agg v7: TWO NODES PER WAVE (half-wave per node), 8 nodes / 256-thr block.
// ---------------------------------------------------------------------------
__global__ __launch_bounds__(256)
void k_agg(const int* __restrict__ cursor, const float4* __restrict__ edata,
           const float4* __restrict__ asrc4, const float4* __restrict__ adst4,
           const unsigned short* __restrict__ x16, unsigned short* __restrict__ sbar)
{
    __shared__ float4 wsh[4][2][CAP];
    int t = threadIdx.x;
    int wv = t >> 6, l = t & 63;
    int h = l >> 5, q = l & 31;
    int n = blockIdx.x * 8 + wv * 2 + h;
    int ne_raw = cursor[n];
    int ne = ne_raw < CAP ? ne_raw : CAP;
    float4 ad = adst4[n];
    const char* xb = (const char*)x16;

    float a0[4] = {0.f,0.f,0.f,0.f};
    float a1[4] = {0.f,0.f,0.f,0.f};
    float a2[4] = {0.f,0.f,0.f,0.f};
    float pd0=0.f, pd1=0.f, pd2=0.f, pa0=0.f, pa1=0.f, pa2=0.f;

    // ---- phase A: half-wave covers slots q and q+32 of its node ----
    #pragma unroll
    for (int base = 0; base < CAP; base += 32) {
        int i = base + q;
        if (i < ne) {
            float4 m0 = edata[(size_t)n * CAP + i];
            int r = __float_as_int(m0.x);
            float4 as = asrc4[r];
            float al0 = m0.y + as.x + ad.x;
            float al1 = m0.z + as.y + ad.y;
            float al2 = m0.w + as.z + ad.z;
            al0 = (al0 >= 0.f) ? al0 : NEG_SLOPE * al0;
            al1 = (al1 >= 0.f) ? al1 : NEG_SLOPE * al1;
            al2 = (al2 >= 0.f) ? al2 : NEG_SLOPE * al2;
            float w0 = __expf(al0), w1 = __expf(al1), w2 = __expf(al2);
            pa0 += m0.y; pa1 += m0.z; pa2 += m0.w;
            pd0 += w0; pd1 += w1; pd2 += w2;
            wsh[wv][h][i] = make_float4(w0, w1, w2, m0.x);
        }
    }
    // wave-synchronous LDS: drain writes before any lane reads
    asm volatile("s_waitcnt lgkmcnt(0)" ::: "memory");
    __builtin_amdgcn_sched_barrier(0);

    // ---- 5-step butterfly within each half-wave (halves stay separate) ----
    #pragma unroll
    for (int s = 16; s; s >>= 1) {
        pd0 += __shfl_xor(pd0, s); pd1 += __shfl_xor(pd1, s); pd2 += __shfl_xor(pd2, s);
        pa0 += __shfl_xor(pa0, s); pa1 += __shfl_xor(pa1, s); pa2 += __shfl_xor(pa2, s);
    }

    // ---- phase B: half-wave walks its node's edges; lane q -> cols 4q..4q+3
    #pragma unroll 2
    for (int i = 0; i < ne; ++i) {
        float4 m = wsh[wv][h][i];
        int r = __float_as_int(m.w);
        uint2 v = *(const uint2*)(xb + (size_t)r * 256 + q * 8);
        float e0 = __uint_as_float(v.x << 16);
        float e1 = __uint_as_float(v.x & 0xFFFF0000u);
        float e2 = __uint_as_float(v.y << 16);
        float e3 = __uint_as_float(v.y & 0xFFFF0000u);
        a0[0] += m.x * e0; a0[1] += m.x * e1; a0[2] += m.x * e2; a0[3] += m.x * e3;
        a1[0] += m.y * e0; a1[1] += m.y * e1; a1[2] += m.y * e2; a1[3] += m.y * e3;
        a2[0] += m.z * e0; a2[1] += m.z * e1; a2[2] += m.z * e2; a2[3] += m.z * e3;
    }

    // ---- self-loop: attr = mean of incoming -> ae_loop = mean of ae ----
    float4 as = asrc4[n];
    float inv = 1.0f / fmaxf((float)ne_raw, 1.0f);
    float al0 = as.x + ad.x + pa0 * inv;
    float al1 = as.y + ad.y + pa1 * inv;
    float al2 = as.z + ad.z + pa2 * inv;
    al0 = (al0 >= 0.f) ? al0 : NEG_SLOPE * al0;
    al1 = (al1 >= 0.f) ? al1 : NEG_SLOPE * al1;
    al2 = (al2 >= 0.f) ? al2 : NEG_SLOPE * al2;
    float w0 = __expf(al0), w1 = __expf(al1), w2 = __expf(al2);
    float d0 = pd0 + w0, d1 = pd1 + w1, d2 = pd2 + w2;
    float i0 = 1.f / d0, i1 = 1.f / d1, i2 = 1.f / d2;

    // ---- epilogue: all 64 lanes store (each half its node) ----
    uint2 xv = *(const uint2*)(xb + (size_t)n * 256 + q * 8);
    float e0 = __uint_as_float(xv.x << 16);
    float e1 = __uint_as_float(xv.x & 0xFFFF0000u);
    float e2 = __uint_as_float(xv.y << 16);
    float e3 = __uint_as_float(xv.y & 0xFFFF0000u);
    uint2* ob = (uint2*)(sbar + (size_t)n * HO);
    unsigned int p0, p1;
    p0 = (unsigned int)f2b((a0[0] + w0 * e0) * i0) | ((unsigned int)f2b((a0[1] + w0 * e1) * i0) << 16);
    p1 = (unsigned int)f2b((a0[2] + w0 * e2) * i0) | ((unsigned int)f2b((a0[3] + w0 * e3) * i0) << 16);
    ob[q] = make_uint2(p0, p1);
    p0 = (unsigned int)f2b((a1[0] + w1 * e0) * i1) | ((unsigned int)f2b((a1[1] + w1 * e1) * i1) << 16);
    p1 = (unsigned int)f2b((a1[2] + w1 * e2) * i1) | ((unsigned int)f2b((a1[3] + w1 * e3) * i1) << 16);
    ob[32 + q] = make_uint2(p0, p1);
    p0 = (unsigned int)f2b((a2[0] + w2 * e0) * i2) | ((unsigned int)f2b((a2[1] + w2 * e1) * i2) << 16);
    p1 = (unsigned int)f2b((a2[2] + w2 * e2) * i2) | ((unsigned int)f2b((a2[3] + w2 * e3) * i2) << 16);
    ob[64 + q] = make_uint2(p0, p1);
}

// ---------------------------------------------------------------------------
// MFMA GEMM + bias + residual + LayerNorm fused:
// out[M][128] = LN( sbar[M][384] @ Q + b2 + x )   Bt = Qt [128][384]
// ---------------------------------------------------------------------------
__global__ __launch_bounds__(256)
void k_mm2_ln(const unsigned short* __restrict__ A, const unsigned short* __restrict__ Bt,
              const float* __restrict__ bias, const float* __restrict__ xres,
              const float* __restrict__ lng, const float* __restrict__ lnb,
              float* __restrict__ out)
{
    __shared__ char lds[24576]; // As [0,8192), Bs [8192,24576)
    const int bm = blockIdx.x * 64;
    const int tid = threadIdx.x, w = tid >> 6, lane = tid & 63;
    const int lrow = lane & 15, lk = lane >> 4;
    const short z0 = 0;
    f32x4 acc[8];
    #pragma unroll
    for (int f = 0; f < 8; ++f) { acc[f][0]=0.f; acc[f][1]=0.f; acc[f][2]=0.f; acc[f][3]=0.f; }

    for (int k0 = 0; k0 < 384; k0 += 64) {
        #pragma unroll
        for (int it = 0; it < 2; ++it) {
            int c = tid + it * 256;
            int row = c >> 3, o = c & 7;
            int grow = bm + row;
            bf16x8 v = {z0,z0,z0,z0,z0,z0,z0,z0};
            if (grow < M_NODES) v = *(const bf16x8*)(A + (size_t)grow * 384 + k0 + o * 8);
            int b = (row * 128 + o * 16) ^ ((row & 7) << 4);
            *(bf16x8*)(lds + b) = v;
        }
        #pragma unroll
        for (int it = 0; it < 4; ++it) {
            int c = tid + it * 256;
            int row = c >> 3, o = c & 7;   // row 0..127
            bf16x8 v = *(const bf16x8*)(Bt + (size_t)row * 384 + k0 + o * 8);
            int b = 8192 + ((row * 128 + o * 16) ^ ((row & 7) << 4));
            *(bf16x8*)(lds + b) = v;
        }
        __syncthreads();
        #pragma unroll
        for (int kk = 0; kk < 2; ++kk) {
            int ar = w * 16 + lrow;
            bf16x8 a = *(const bf16x8*)(lds + ((ar * 128 + kk * 64 + lk * 16) ^ ((lrow & 7) << 4)));
            #pragma unroll
            for (int f = 0; f < 8; ++f) {
                int br = 16 * f + lrow;
                bf16x8 bb = *(const bf16x8*)(lds + 8192 + ((br * 128 + kk * 64 + lk * 16) ^ ((lrow & 7) << 4)));
                acc[f] = __builtin_amdgcn_mfma_f32_16x16x32_bf16(a, bb, acc[f], 0, 0, 0);
            }
        }
        __syncthreads();
    }

    // fused bias + residual + LayerNorm epilogue
    int cols[8]; float bs[8], gg[8], bbv[8];
    #pragma unroll
    for (int f = 0; f < 8; ++f) {
        cols[f] = 16 * f + lrow;
        bs[f] = bias[cols[f]];
        gg[f] = lng[cols[f]];
        bbv[f] = lnb[cols[f]];
    }
    #pragma unroll
    for (int rg = 0; rg < 4; ++rg) {
        int grow = bm + w * 16 + lk * 4 + rg;
        bool ok = grow < M_NODES;
        float h[8];
        float s = 0.f;
        #pragma unroll
        for (int f = 0; f < 8; ++f) {
            float hv = 0.f;
            if (ok) hv = acc[f][rg] + bs[f] + xres[(size_t)grow * 128 + cols[f]];
            h[f] = hv;
            s += hv;
        }
        #pragma unroll
        for (int m = 1; m < 16; m <<= 1) s += __shfl_xor(s, m);
        float mu = s * (1.0f / 128.0f);
        float vv = 0.f;
        #pragma unroll
        for (int f = 0; f < 8; ++f) { float d = h[f] - mu; vv += d * d; }
        #pragma unroll
        for (int m = 1; m < 16; m <<= 1) vv += __shfl_xor(vv, m);
        float rs = rsqrtf(vv * (1.0f / 128.0f) + LN_EPS);
        if (ok) {
            #pragma unroll
            for (int f = 0; f < 8; ++f)
                out[(size_t)grow * 128 + cols[f]] = (h[f] - mu) * rs * gg[f] + bbv[f];
        }
    }
}

// ---------------------------------------------------------------------------
extern "C" void kernel_launch(void* const* d_in, const int* in_sizes, int n_in,
                              void* d_out, int out_size, void* d_ws, size_t ws_size,
                              hipStream_t stream)
{
    const float* x    = (const float*)d_in[0];
    const int*   ei   = (const int*)  d_in[1];
    const float* ea   = (const float*)d_in[2];
    const float* W    = (const float*)d_in[3];
    const float* Wed  = (const float*)d_in[4];
    const float* asv  = (const float*)d_in[5];
    const float* adv  = (const float*)d_in[6];
    const float* aev  = (const float*)d_in[7];
    const float* gb   = (const float*)d_in[8];
    const float* lw   = (const float*)d_in[9];
    const float* lb   = (const float*)d_in[10];
    const float* lng  = (const float*)d_in[11];
    const float* lnb  = (const float*)d_in[12];
    float* out = (float*)d_out;

    char* wsp = (char*)d_ws;
    size_t off = 0;
    auto alloc = [&](size_t bytes) -> void* {
        void* p = wsp + off;
        off += bytes;
        off = (off + 255) & ~(size_t)255;
        return p;
    };

    // zero-init region (cursor only)
    int*   cursor  = (int*)  alloc((size_t)M_NODES * 4);
    size_t zero_bytes = off;
    float* small   = (float*)alloc(816 * 4);
    float* b2      = (float*)alloc(128 * 4);
    float4* asrc4  = (float4*)alloc((size_t)M_NODES * 16);
    float4* adst4  = (float4*)alloc((size_t)M_NODES * 16);
    float4* edata  = (float4*)alloc((size_t)M_NODES * CAP * 16);   // 51.2 MB
    unsigned short* x16   = (unsigned short*)alloc((size_t)M_NODES * IN_F * 2);
    unsigned short* Qt16  = (unsigned short*)alloc((size_t)OUT_F * HO * 2);
    unsigned short* sbar  = (unsigned short*)alloc((size_t)M_NODES * HO * 2);
    (void)ws_size; (void)in_sizes; (void)n_in; (void)out_size;

    (void)hipMemsetAsync(d_ws, 0, zero_bytes, stream);

    k_small<<<432, 64, 0, stream>>>(W, Wed, asv, adv, aev, small);
    k_pre<<<PB_TOT, 256, 0, stream>>>(x, W, lw, gb, lb, ei, ea, small,
                                      asrc4, adst4, x16, cursor, edata, Qt16, b2);
    k_agg<<<M_NODES / 8, 256, 0, stream>>>(cursor, edata, asrc4, adst4, x16, sbar);
    k_mm2_ln<<<(M_NODES + 63) / 64, 256, 0, stream>>>(sbar, Qt16, b2, x, lng, lnb, out);
}

// Round 17
// 124.916 us; speedup vs baseline: 1.1370x; 1.0615x over previous
//
#include <hip/hip_runtime.h>
#include <hip/hip_bf16.h>
#include <math.h>

#define M_NODES 50000
#define IN_F    128
#define OUT_F   128
#define NH      3
#define ED_F    16
#define NE      800000
#define HO      (NH * OUT_F)   // 384
#define NEG_SLOPE 0.2f
#define LN_EPS    1e-5f
#define CAP     64             // node bucket capacity; P(deg>64)~1e-18

// k_pre block ranges (256-thread blocks) — r14 layout (2 edges/thread: best)
#define PB_ATTN 782                   // 64 nodes/block (4 lanes per node)
#define PB_FILL (PB_ATTN + 1563)      // 2345: 512 edges/block (2 per thread)
#define PB_PQ   (PB_FILL + 192)       // 2537: 2 outputs/block
#define PB_TOT  (PB_PQ + 128)         // 2665: bias2, 1 column/block

typedef __attribute__((ext_vector_type(8))) short bf16x8;
typedef __attribute__((ext_vector_type(4))) float f32x4;

__device__ __forceinline__ float b2f(unsigned short u) {
    unsigned int x = ((unsigned int)u) << 16;
    return __uint_as_float(x);
}
__device__ __forceinline__ unsigned short f2b(float f) {
    __hip_bfloat16 h = __float2bfloat16(f);
    return *(unsigned short*)&h;
}

// ---------------------------------------------------------------------------
// K_small: folded attention vectors, one block (64 thr) per output.
// ALSO zeroes cursor (replaces the hipMemsetAsync dispatch).
// small layout: [0,384) srcT h*128+k | [384,768) dstT h*128+k | [768,816) We(d*3+h)
// ---------------------------------------------------------------------------
__global__ __launch_bounds__(64)
void k_small(const float* __restrict__ W, const float* __restrict__ Wed,
             const float* __restrict__ a_s, const float* __restrict__ a_d,
             const float* __restrict__ a_e, float* __restrict__ small,
             int* __restrict__ cursor)
{
    int o = blockIdx.x, l = threadIdx.x;
    // zero cursor: 432*64 threads x 2 entries covers 50000
    int zi = (o * 64 + l) * 2;
    if (zi < M_NODES) cursor[zi] = 0;
    if (zi + 1 < M_NODES) cursor[zi + 1] = 0;
    if (o < 384) {
        int k = o / 3, h = o - k * 3;
        float wA = W[(size_t)k * HO + h * 128 + l];
        float wB = W[(size_t)k * HO + h * 128 + 64 + l];
        float s1 = wA * a_s[h * 128 + l] + wB * a_s[h * 128 + 64 + l];
        float s2 = wA * a_d[h * 128 + l] + wB * a_d[h * 128 + 64 + l];
        #pragma unroll
        for (int s = 32; s; s >>= 1) { s1 += __shfl_xor(s1, s); s2 += __shfl_xor(s2, s); }
        if (l == 0) { small[h * 128 + k] = s1; small[384 + h * 128 + k] = s2; }
    } else {
        int u = o - 384;
        int d = u / 3, h = u - d * 3;
        float s = Wed[(size_t)d * HO + h * 128 + l] * a_e[h * 128 + l]
                + Wed[(size_t)d * HO + h * 128 + 64 + l] * a_e[h * 128 + 64 + l];
        #pragma unroll
        for (int ss = 32; ss; ss >>= 1) s += __shfl_xor(s, ss);
        if (l == 0) small[768 + u] = s;
    }
}

// ---------------------------------------------------------------------------
// K_pre mega-kernel (256-thr blocks): 4 block-ranged sections that overlap
// on the machine. Sections MUST stay merged (r11 vs r13: ~15us of overlap).
// Fill MLP sweet spot = 2 edges/thread (r13:1=73us, r14:2=62us, r16:4=70us).
//  [0, 782)       attn: 64 nodes/block, 4 lanes/node; asrc/adst + x->bf16.
//  [782, 2345)    fill: 512 edges/block, 2 independent chains per thread.
//  [2345, 2537)   prep_q: 2 outputs/block
//  [2537, 2665)   bias2: 1 column/block, 256-thread reduce
// ---------------------------------------------------------------------------
__global__ __launch_bounds__(256)
void k_pre(const float* __restrict__ x, const float* __restrict__ W,
           const float* __restrict__ lw, const float* __restrict__ gb,
           const float* __restrict__ lb, const int* __restrict__ ei,
           const float* __restrict__ ea, const float* __restrict__ small,
           float4* __restrict__ asrc4, float4* __restrict__ adst4,
           unsigned short* __restrict__ x16, int* __restrict__ cursor,
           float4* __restrict__ edata,
           unsigned short* __restrict__ Qt, float* __restrict__ b2)
{
    int b = blockIdx.x, t = threadIdx.x;
    if (b < PB_ATTN) {
        // padded LDS: row = s*12 + h*4 + j (24 rows x 36 floats), conflict-free
        __shared__ float smp[24 * 36];
        for (int i = t; i < 768; i += 256) {
            int s = i / 384;
            int rem = i - s * 384;
            int h = rem >> 7, rem2 = rem & 127;
            int j = rem2 >> 5, col = rem2 & 31;
            smp[(s * 12 + h * 4 + j) * 36 + col] = small[i];
        }
        __syncthreads();
        int g = t >> 2, j = t & 3;
        int n = b * 64 + g;
        if (n >= M_NODES) return;
        const float4* xr = (const float4*)x + (size_t)n * 32 + j * 8;
        float4 xv[8];
        #pragma unroll
        for (int i = 0; i < 8; ++i) xv[i] = xr[i];
        unsigned int pk[16];
        #pragma unroll
        for (int i = 0; i < 8; ++i) {
            pk[2*i]   = (unsigned int)f2b(xv[i].x) | ((unsigned int)f2b(xv[i].y) << 16);
            pk[2*i+1] = (unsigned int)f2b(xv[i].z) | ((unsigned int)f2b(xv[i].w) << 16);
        }
        uint4* xo = (uint4*)(x16 + (size_t)n * IN_F + j * 32);
        xo[0] = make_uint4(pk[0],  pk[1],  pk[2],  pk[3]);
        xo[1] = make_uint4(pk[4],  pk[5],  pk[6],  pk[7]);
        xo[2] = make_uint4(pk[8],  pk[9],  pk[10], pk[11]);
        xo[3] = make_uint4(pk[12], pk[13], pk[14], pk[15]);
        float p[3] = {0.f,0.f,0.f}, q[3] = {0.f,0.f,0.f};
        #pragma unroll
        for (int i = 0; i < 8; ++i) {
            float4 v = xv[i];
            #pragma unroll
            for (int h = 0; h < 3; ++h) {
                float4 ws = *(const float4*)&smp[(h * 4 + j) * 36 + i * 4];
                float4 wd = *(const float4*)&smp[(12 + h * 4 + j) * 36 + i * 4];
                p[h] += v.x * ws.x + v.y * ws.y + v.z * ws.z + v.w * ws.w;
                q[h] += v.x * wd.x + v.y * wd.y + v.z * wd.z + v.w * wd.w;
            }
        }
        #pragma unroll
        for (int h = 0; h < 3; ++h) {
            p[h] += __shfl_xor(p[h], 1); p[h] += __shfl_xor(p[h], 2);
            q[h] += __shfl_xor(q[h], 1); q[h] += __shfl_xor(q[h], 2);
        }
        if (j == 0) {
            asrc4[n] = make_float4(p[0], p[1], p[2], 0.f);
            adst4[n] = make_float4(q[0], q[1], q[2], 0.f);
        }
    } else if (b < PB_FILL) {
        int e0 = (b - PB_ATTN) * 512 + t;      // edges e0 and e0+256
        int e1 = e0 + 256;
        bool v0 = e0 < NE;
        bool v1 = e1 < NE;
        int r0 = 0, c0 = 0, r1 = 0, c1 = 0, pos0 = 0, pos1 = 0;
        if (v0) {
            r0 = ei[e0]; c0 = ei[NE + e0];
            pos0 = atomicAdd(&cursor[c0], 1);
        }
        if (v1) {
            r1 = ei[e1]; c1 = ei[NE + e1];
            pos1 = atomicAdd(&cursor[c1], 1);
        }
        const float* Wev = small + 768;
        if (v0) {
            const float4* p = (const float4*)(ea + (size_t)e0 * 16);
            float4 q0 = p[0], q1 = p[1], q2 = p[2], q3 = p[3];
            float v[16] = {q0.x,q0.y,q0.z,q0.w, q1.x,q1.y,q1.z,q1.w,
                           q2.x,q2.y,q2.z,q2.w, q3.x,q3.y,q3.z,q3.w};
            float ae[3];
            #pragma unroll
            for (int h = 0; h < 3; ++h) {
                float s = 0.f;
                #pragma unroll
                for (int d = 0; d < 16; ++d) s += v[d] * Wev[d * 3 + h];
                ae[h] = s;
            }
            if (pos0 < CAP)
                edata[(size_t)c0 * CAP + pos0] =
                    make_float4(__int_as_float(r0), ae[0], ae[1], ae[2]);
        }
        if (v1) {
            const float4* p = (const float4*)(ea + (size_t)e1 * 16);
            float4 q0 = p[0], q1 = p[1], q2 = p[2], q3 = p[3];
            float v[16] = {q0.x,q0.y,q0.z,q0.w, q1.x,q1.y,q1.z,q1.w,
                           q2.x,q2.y,q2.z,q2.w, q3.x,q3.y,q3.z,q3.w};
            float ae[3];
            #pragma unroll
            for (int h = 0; h < 3; ++h) {
                float s = 0.f;
                #pragma unroll
                for (int d = 0; d < 16; ++d) s += v[d] * Wev[d * 3 + h];
                ae[h] = s;
            }
            if (pos1 < CAP)
                edata[(size_t)c1 * CAP + pos1] =
                    make_float4(__int_as_float(r1), ae[0], ae[1], ae[2]);
        }
    } else if (b < PB_PQ) {
        int i = (b - PB_FILL) * 2 + (t >> 7);  // 0..383 = h*128+tt
        int h = i >> 7, tt = i & 127;
        int j = t & 127;
        float s = 0.f;
        const float* wrow = W + (size_t)tt * HO + h * 128;
        const float* lcol = lw + (size_t)(h * 128) * 128 + j;
        #pragma unroll 4
        for (int c = 0; c < 128; ++c)
            s += wrow[c] * lcol[(size_t)c * 128];
        Qt[(size_t)j * HO + i] = f2b(s);
    } else {
        __shared__ float red[4];
        int j = b - PB_PQ;
        float s = 0.f;
        for (int i = t; i < HO; i += 256) s += gb[i] * lw[(size_t)i * 128 + j];
        #pragma unroll
        for (int k = 32; k; k >>= 1) s += __shfl_xor(s, k);
        int w = t >> 6, lane = t & 63;
        if (lane == 0) red[w] = s;
        __syncthreads();
        if (t == 0) b2[j] = lb[j] + red[0] + red[1] + red[2] + red[3];
    }
}

// ---------------------------------------------------------------------------
// K_agg v7: TWO NODES PER WAVE (half-wave per node), 8 nodes / 256-thr block.
// Phase A uses NON-TEMPORAL loads for the zero-reuse edata stream (51MB) so
// it doesn't evict the L3-resident x16 that phase B gathers from.
// ---------------------------------------------------------------------------
__global__ __launch_bounds__(256)
void k_agg(const int* __restrict__ cursor, const float4* __restrict__ edata,
           const float4* __restrict__ asrc4, const float4* __restrict__ adst4,
           const unsigned short* __restrict__ x16, unsigned short* __restrict__ sbar)
{
    __shared__ float4 wsh[4][2][CAP];
    int t = threadIdx.x;
    int wv = t >> 6, l = t & 63;
    int h = l >> 5, q = l & 31;
    int n = blockIdx.x * 8 + wv * 2 + h;
    int ne_raw = cursor[n];
    int ne = ne_raw < CAP ? ne_raw : CAP;
    float4 ad = adst4[n];
    const char* xb = (const char*)x16;

    float a0[4] = {0.f,0.f,0.f,0.f};
    float a1[4] = {0.f,0.f,0.f,0.f};
    float a2[4] = {0.f,0.f,0.f,0.f};
    float pd0=0.f, pd1=0.f, pd2=0.f, pa0=0.f, pa1=0.f, pa2=0.f;

    // ---- phase A: half-wave covers slots q and q+32 of its node ----
    #pragma unroll
    for (int base = 0; base < CAP; base += 32) {
        int i = base + q;
        if (i < ne) {
            f32x4 m0 = __builtin_nontemporal_load(
                (const f32x4*)(edata + (size_t)n * CAP + i));
            int r = __float_as_int(m0[0]);
            float4 as = asrc4[r];
            float al0 = m0[1] + as.x + ad.x;
            float al1 = m0[2] + as.y + ad.y;
            float al2 = m0[3] + as.z + ad.z;
            al0 = (al0 >= 0.f) ? al0 : NEG_SLOPE * al0;
            al1 = (al1 >= 0.f) ? al1 : NEG_SLOPE * al1;
            al2 = (al2 >= 0.f) ? al2 : NEG_SLOPE * al2;
            float w0 = __expf(al0), w1 = __expf(al1), w2 = __expf(al2);
            pa0 += m0[1]; pa1 += m0[2]; pa2 += m0[3];
            pd0 += w0; pd1 += w1; pd2 += w2;
            wsh[wv][h][i] = make_float4(w0, w1, w2, m0[0]);
        }
    }
    // wave-synchronous LDS: drain writes before any lane reads
    asm volatile("s_waitcnt lgkmcnt(0)" ::: "memory");
    __builtin_amdgcn_sched_barrier(0);

    // ---- 5-step butterfly within each half-wave (halves stay separate) ----
    #pragma unroll
    for (int s = 16; s; s >>= 1) {
        pd0 += __shfl_xor(pd0, s); pd1 += __shfl_xor(pd1, s); pd2 += __shfl_xor(pd2, s);
        pa0 += __shfl_xor(pa0, s); pa1 += __shfl_xor(pa1, s); pa2 += __shfl_xor(pa2, s);
    }

    // ---- phase B: half-wave walks its node's edges; lane q -> cols 4q..4q+3
    #pragma unroll 2
    for (int i = 0; i < ne; ++i) {
        float4 m = wsh[wv][h][i];
        int r = __float_as_int(m.w);
        uint2 v = *(const uint2*)(xb + (size_t)r * 256 + q * 8);
        float e0 = __uint_as_float(v.x << 16);
        float e1 = __uint_as_float(v.x & 0xFFFF0000u);
        float e2 = __uint_as_float(v.y << 16);
        float e3 = __uint_as_float(v.y & 0xFFFF0000u);
        a0[0] += m.x * e0; a0[1] += m.x * e1; a0[2] += m.x * e2; a0[3] += m.x * e3;
        a1[0] += m.y * e0; a1[1] += m.y * e1; a1[2] += m.y * e2; a1[3] += m.y * e3;
        a2[0] += m.z * e0; a2[1] += m.z * e1; a2[2] += m.z * e2; a2[3] += m.z * e3;
    }

    // ---- self-loop: attr = mean of incoming -> ae_loop = mean of ae ----
    float4 as = asrc4[n];
    float inv = 1.0f / fmaxf((float)ne_raw, 1.0f);
    float al0 = as.x + ad.x + pa0 * inv;
    float al1 = as.y + ad.y + pa1 * inv;
    float al2 = as.z + ad.z + pa2 * inv;
    al0 = (al0 >= 0.f) ? al0 : NEG_SLOPE * al0;
    al1 = (al1 >= 0.f) ? al1 : NEG_SLOPE * al1;
    al2 = (al2 >= 0.f) ? al2 : NEG_SLOPE * al2;
    float w0 = __expf(al0), w1 = __expf(al1), w2 = __expf(al2);
    float d0 = pd0 + w0, d1 = pd1 + w1, d2 = pd2 + w2;
    float i0 = 1.f / d0, i1 = 1.f / d1, i2 = 1.f / d2;

    // ---- epilogue: all 64 lanes store (each half its node) ----
    uint2 xv = *(const uint2*)(xb + (size_t)n * 256 + q * 8);
    float e0 = __uint_as_float(xv.x << 16);
    float e1 = __uint_as_float(xv.x & 0xFFFF0000u);
    float e2 = __uint_as_float(xv.y << 16);
    float e3 = __uint_as_float(xv.y & 0xFFFF0000u);
    uint2* ob = (uint2*)(sbar + (size_t)n * HO);
    unsigned int p0, p1;
    p0 = (unsigned int)f2b((a0[0] + w0 * e0) * i0) | ((unsigned int)f2b((a0[1] + w0 * e1) * i0) << 16);
    p1 = (unsigned int)f2b((a0[2] + w0 * e2) * i0) | ((unsigned int)f2b((a0[3] + w0 * e3) * i0) << 16);
    ob[q] = make_uint2(p0, p1);
    p0 = (unsigned int)f2b((a1[0] + w1 * e0) * i1) | ((unsigned int)f2b((a1[1] + w1 * e1) * i1) << 16);
    p1 = (unsigned int)f2b((a1[2] + w1 * e2) * i1) | ((unsigned int)f2b((a1[3] + w1 * e3) * i1) << 16);
    ob[32 + q] = make_uint2(p0, p1);
    p0 = (unsigned int)f2b((a2[0] + w2 * e0) * i2) | ((unsigned int)f2b((a2[1] + w2 * e1) * i2) << 16);
    p1 = (unsigned int)f2b((a2[2] + w2 * e2) * i2) | ((unsigned int)f2b((a2[3] + w2 * e3) * i2) << 16);
    ob[64 + q] = make_uint2(p0, p1);
}

// ---------------------------------------------------------------------------
// MFMA GEMM + bias + residual + LayerNorm fused:
// out[M][128] = LN( sbar[M][384] @ Q + b2 + x )   Bt = Qt [128][384]
// ---------------------------------------------------------------------------
__global__ __launch_bounds__(256)
void k_mm2_ln(const unsigned short* __restrict__ A, const unsigned short* __restrict__ Bt,
              const float* __restrict__ bias, const float* __restrict__ xres,
              const float* __restrict__ lng, const float* __restrict__ lnb,
              float* __restrict__ out)
{
    __shared__ char lds[24576]; // As [0,8192), Bs [8192,24576)
    const int bm = blockIdx.x * 64;
    const int tid = threadIdx.x, w = tid >> 6, lane = tid & 63;
    const int lrow = lane & 15, lk = lane >> 4;
    const short z0 = 0;
    f32x4 acc[8];
    #pragma unroll
    for (int f = 0; f < 8; ++f) { acc[f][0]=0.f; acc[f][1]=0.f; acc[f][2]=0.f; acc[f][3]=0.f; }

    for (int k0 = 0; k0 < 384; k0 += 64) {
        #pragma unroll
        for (int it = 0; it < 2; ++it) {
            int c = tid + it * 256;
            int row = c >> 3, o = c & 7;
            int grow = bm + row;
            bf16x8 v = {z0,z0,z0,z0,z0,z0,z0,z0};
            if (grow < M_NODES) v = *(const bf16x8*)(A + (size_t)grow * 384 + k0 + o * 8);
            int b = (row * 128 + o * 16) ^ ((row & 7) << 4);
            *(bf16x8*)(lds + b) = v;
        }
        #pragma unroll
        for (int it = 0; it < 4; ++it) {
            int c = tid + it * 256;
            int row = c >> 3, o = c & 7;   // row 0..127
            bf16x8 v = *(const bf16x8*)(Bt + (size_t)row * 384 + k0 + o * 8);
            int b = 8192 + ((row * 128 + o * 16) ^ ((row & 7) << 4));
            *(bf16x8*)(lds + b) = v;
        }
        __syncthreads();
        #pragma unroll
        for (int kk = 0; kk < 2; ++kk) {
            int ar = w * 16 + lrow;
            bf16x8 a = *(const bf16x8*)(lds + ((ar * 128 + kk * 64 + lk * 16) ^ ((lrow & 7) << 4)));
            #pragma unroll
            for (int f = 0; f < 8; ++f) {
                int br = 16 * f + lrow;
                bf16x8 bb = *(const bf16x8*)(lds + 8192 + ((br * 128 + kk * 64 + lk * 16) ^ ((lrow & 7) << 4)));
                acc[f] = __builtin_amdgcn_mfma_f32_16x16x32_bf16(a, bb, acc[f], 0, 0, 0);
            }
        }
        __syncthreads();
    }

    // fused bias + residual + LayerNorm epilogue
    int cols[8]; float bs[8], gg[8], bbv[8];
    #pragma unroll
    for (int f = 0; f < 8; ++f) {
        cols[f] = 16 * f + lrow;
        bs[f] = bias[cols[f]];
        gg[f] = lng[cols[f]];
        bbv[f] = lnb[cols[f]];
    }
    #pragma unroll
    for (int rg = 0; rg < 4; ++rg) {
        int grow = bm + w * 16 + lk * 4 + rg;
        bool ok = grow < M_NODES;
        float h[8];
        float s = 0.f;
        #pragma unroll
        for (int f = 0; f < 8; ++f) {
            float hv = 0.f;
            if (ok) hv = acc[f][rg] + bs[f] + xres[(size_t)grow * 128 + cols[f]];
            h[f] = hv;
            s += hv;
        }
        #pragma unroll
        for (int m = 1; m < 16; m <<= 1) s += __shfl_xor(s, m);
        float mu = s * (1.0f / 128.0f);
        float vv = 0.f;
        #pragma unroll
        for (int f = 0; f < 8; ++f) { float d = h[f] - mu; vv += d * d; }
        #pragma unroll
        for (int m = 1; m < 16; m <<= 1) vv += __shfl_xor(vv, m);
        float rs = rsqrtf(vv * (1.0f / 128.0f) + LN_EPS);
        if (ok) {
            #pragma unroll
            for (int f = 0; f < 8; ++f)
                out[(size_t)grow * 128 + cols[f]] = (h[f] - mu) * rs * gg[f] + bbv[f];
        }
    }
}

// ---------------------------------------------------------------------------
extern "C" void kernel_launch(void* const* d_in, const int* in_sizes, int n_in,
                              void* d_out, int out_size, void* d_ws, size_t ws_size,
                              hipStream_t stream)
{
    const float* x    = (const float*)d_in[0];
    const int*   ei   = (const int*)  d_in[1];
    const float* ea   = (const float*)d_in[2];
    const float* W    = (const float*)d_in[3];
    const float* Wed  = (const float*)d_in[4];
    const float* asv  = (const float*)d_in[5];
    const float* adv  = (const float*)d_in[6];
    const float* aev  = (const float*)d_in[7];
    const float* gb   = (const float*)d_in[8];
    const float* lw   = (const float*)d_in[9];
    const float* lb   = (const float*)d_in[10];
    const float* lng  = (const float*)d_in[11];
    const float* lnb  = (const float*)d_in[12];
    float* out = (float*)d_out;

    char* wsp = (char*)d_ws;
    size_t off = 0;
    auto alloc = [&](size_t bytes) -> void* {
        void* p = wsp + off;
        off += bytes;
        off = (off + 255) & ~(size_t)255;
        return p;
    };

    int*   cursor  = (int*)  alloc((size_t)M_NODES * 4);
    float* small   = (float*)alloc(816 * 4);
    float* b2      = (float*)alloc(128 * 4);
    float4* asrc4  = (float4*)alloc((size_t)M_NODES * 16);
    float4* adst4  = (float4*)alloc((size_t)M_NODES * 16);
    float4* edata  = (float4*)alloc((size_t)M_NODES * CAP * 16);   // 51.2 MB
    unsigned short* x16   = (unsigned short*)alloc((size_t)M_NODES * IN_F * 2);
    unsigned short* Qt16  = (unsigned short*)alloc((size_t)OUT_F * HO * 2);
    unsigned short* sbar  = (unsigned short*)alloc((size_t)M_NODES * HO * 2);
    (void)ws_size; (void)in_sizes; (void)n_in; (void)out_size;

    // cursor is zeroed inside k_small (no memset dispatch)
    k_small<<<432, 64, 0, stream>>>(W, Wed, asv, adv, aev, small, cursor);
    k_pre<<<PB_TOT, 256, 0, stream>>>(x, W, lw, gb, lb, ei, ea, small,
                                      asrc4, adst4, x16, cursor, edata, Qt16, b2);
    k_agg<<<M_NODES / 8, 256, 0, stream>>>(cursor, edata, asrc4, adst4, x16, sbar);
    k_mm2_ln<<<(M_NODES + 63) / 64, 256, 0, stream>>>(sbar, Qt16, b2, x, lng, lnb, out);
}